// Round 7
// baseline (193.595 us; speedup 1.0000x reference)
//
#include <hip/hip_runtime.h>
#include <hip/hip_fp16.h>

#define HH 256
#define WW 256
#define KK 81
#define PLANE (HH * WW)

// Pack [B,3,H,W] fp32 -> [B,H,W] ushort4 of fp16 (c0,c1,c2,0): one 8 B cell
// carries all 3 color groups for a pixel. dword0 = c0|c1<<16, dword1 = c2.
__global__ __launch_bounds__(256) void pack_kernel(const float* __restrict__ in,
                                                   ushort4* __restrict__ img) {
    int idx = blockIdx.x * 256 + threadIdx.x;  // b*PLANE + pix
    int b = idx >> 16;
    int pix = idx & 0xFFFF;
    const float* base = in + (size_t)b * 3 * PLANE + pix;
    _Float16 h0 = (_Float16)base[0];
    _Float16 h1 = (_Float16)base[PLANE];
    _Float16 h2 = (_Float16)base[2 * PLANE];
    ushort4 u;
    u.x = __builtin_bit_cast(unsigned short, h0);
    u.y = __builtin_bit_cast(unsigned short, h1);
    u.z = __builtin_bit_cast(unsigned short, h2);
    u.w = 0;
    img[idx] = u;
}

__device__ __forceinline__ void acc3(float w, unsigned int pa, unsigned int pb,
                                     float& ax, float& ay, float& az) {
    __half2 ha = __builtin_bit_cast(__half2, pa);
    __half2 hb = __builtin_bit_cast(__half2, pb);
    ax = fmaf(w, __low2float(ha), ax);   // v_fma_mix_f32 (lo)
    ay = fmaf(w, __high2float(ha), ay);  // v_fma_mix_f32 (hi)
    az = fmaf(w, __low2float(hb), az);
}

// CACHE-GATHER kernel (round 7): NO LDS tile, no staging, no mid-loop
// barriers. Each tap's 4 bilinear corners are 4 clamped global_load_dwordx2
// from the 1 MB packed image; per-corner validity multiplies the weight
// (exact DCNv2 zero-pad semantics -> the old "escape" path IS the main path,
// all special-casing gone). A wave's 81-tap footprint (~17 KB) fits L1
// (32 KB), so the cache hierarchy plays the role the LDS tile did, without
// staging cost, bank conflicts, or barrier coupling.
//
// Block = 64-px strip x 2 waves (split-k: wave0 taps 0..40, wave1 41..80),
// 768 B LDS reduce. Grid 2048 blocks -> 8 blocks/CU resident, 16 waves/CU
// (4/SIMD) to hide gather latency. Stream loads (dy,dx,m) keep round 5's
// uniform-SGPR-base + lane-offset diet.
__global__ __launch_bounds__(128, 4) void dcn_kernel(
    const ushort4* __restrict__ img,
    const float* __restrict__ offset,
    const float* __restrict__ mask,
    const float* __restrict__ weight,
    const float* __restrict__ bias,
    float* __restrict__ out) {
    __shared__ float red[3][64];           // 768 B: wave1 -> wave0 combine

    const int t = threadIdx.x;             // 0..127
    const int wv = t >> 6;
    const int l = t & 63;
    const int bx = blockIdx.x;
    const int b = blockIdx.y;
    const int ho = bx >> 2;                // output row
    const int xo = (bx & 3) * 64;          // strip origin col
    const uint2* ibq = (const uint2*)img + (size_t)b * PLANE;

    // wave's tap range: wave0 [0,41), wave1 [41,81)
    const int kb = wv * 41;
    const int nk = 41 - wv;                // 41 or 40

    // uniform stream bases (SGPR) + lane offset
    const float* orow = offset + (size_t)b * 2 * KK * PLANE + (size_t)(2 * kb) * PLANE
                        + (size_t)ho * WW + xo;
    const float* mrow = mask + (size_t)b * KK * PLANE + (size_t)kb * PLANE
                        + (size_t)ho * WW + xo;

    const int wo = xo + l;                 // this lane's output col
    float ax = 0.f, ay = 0.f, az = 0.f;

    int ky = (kb == 41) ? 4 : 0;           // kb/9, kb%9 (uniform)
    int kxi = (kb == 41) ? 5 : 0;

#pragma unroll 4
    for (int j = 0; j < nk; ++j) {
        const int k = kb + j;              // uniform
        float dy = orow[(size_t)(2 * j) * PLANE + l];
        float dx = orow[(size_t)(2 * j + 1) * PLANE + l];
        float m = mrow[(size_t)j * PLANE + l];
        float wkv = weight[k];             // wave-uniform s_load

        // y: py = (ho-4+ky) + dy ; integer part split off exactly
        float yf = floorf(dy);
        float wy = dy - yf;                // == fract(py)
        int y0 = (int)yf + (ho - 4 + ky);
        // x: px = wo + (dx + (kxi-4))
        float fx = dx + (float)(kxi - 4);
        float xf = floorf(fx);
        float wx = fx - xf;
        int x0 = (int)xf + wo;
        int y1 = y0 + 1, x1 = x0 + 1;

        // per-corner validity (zero-pad semantics), clamped gather indices
        float va0 = ((unsigned)y0 < (unsigned)HH) ? 1.f : 0.f;
        float va1 = ((unsigned)y1 < (unsigned)HH) ? 1.f : 0.f;
        float vb0 = ((unsigned)x0 < (unsigned)WW) ? 1.f : 0.f;
        float vb1 = ((unsigned)x1 < (unsigned)WW) ? 1.f : 0.f;
        int y0c = min(max(y0, 0), HH - 1);
        int y1c = min(max(y1, 0), HH - 1);
        int x0c = min(max(x0, 0), WW - 1);
        int x1c = min(max(x1, 0), WW - 1);

        float mw = m * wkv;
        float w1y = wy * mw, w0y = mw - w1y;
        float u1 = 1.f - wx;
        float w00 = w0y * u1 * va0 * vb0;
        float w01 = w0y * wx * va0 * vb1;
        float w10 = w1y * u1 * va1 * vb0;
        float w11 = w1y * wx * va1 * vb1;

        // 4 clamped gathers through L1/L2 (8 B each)
        uint2 q00 = ibq[y0c * WW + x0c];
        uint2 q01 = ibq[y0c * WW + x1c];
        uint2 q10 = ibq[y1c * WW + x0c];
        uint2 q11 = ibq[y1c * WW + x1c];

        acc3(w00, q00.x, q00.y, ax, ay, az);
        acc3(w01, q01.x, q01.y, ax, ay, az);
        acc3(w10, q10.x, q10.y, ax, ay, az);
        acc3(w11, q11.x, q11.y, ax, ay, az);

        if (++kxi == 9) {
            kxi = 0;
            ++ky;
        }
    }

    // split-k combine: wave1 publishes, wave0 adds + stores
    if (wv == 1) {
        red[0][l] = ax;
        red[1][l] = ay;
        red[2][l] = az;
    }
    __syncthreads();
    if (wv == 0) {
        float bs = bias[0];
        float* ob = out + (size_t)b * 3 * PLANE + (size_t)ho * WW + xo + l;
        ob[0] = ax + red[0][l] + bs;
        ob[PLANE] = ay + red[1][l] + bs;
        ob[2 * PLANE] = az + red[2][l] + bs;
    }
}

extern "C" void kernel_launch(void* const* d_in, const int* in_sizes, int n_in,
                              void* d_out, int out_size, void* d_ws, size_t ws_size,
                              hipStream_t stream) {
    const float* input = (const float*)d_in[0];
    const float* offset = (const float*)d_in[1];
    const float* mask = (const float*)d_in[2];
    const float* weight = (const float*)d_in[3];
    const float* bias = (const float*)d_in[4];
    float* out = (float*)d_out;

    const int B = in_sizes[0] / (3 * PLANE);  // 2
    ushort4* img = (ushort4*)d_ws;            // 1 MB packed fp16 image

    pack_kernel<<<B * PLANE / 256, 256, 0, stream>>>(input, img);
    dim3 grid(HH * 4, B);                     // 4 strip-blocks per row
    dcn_kernel<<<grid, 128, 0, stream>>>(img, offset, mask, weight, bias, out);
}

// Round 8
// 171.479 us; speedup vs baseline: 1.1290x; 1.1290x over previous
//
#include <hip/hip_runtime.h>
#include <hip/hip_fp16.h>

#define HH 256
#define WW 256
#define KK 81
#define PLANE (HH * WW)
#define SLK 10            // halo
#define TR 21             // tile rows: [ho-10, ho+10]
#define TCW 276           // tile cols: [-10, 266)
#define TABW (TR * TCW)   // 5796 cells

// Pack [B,3,H,W] fp32 -> [B,H,W] ushort4 of fp16 (c0,c1,c2,0).
__global__ __launch_bounds__(256) void pack_kernel(const float* __restrict__ in,
                                                   ushort4* __restrict__ img) {
    int idx = blockIdx.x * 256 + threadIdx.x;  // b*PLANE + pix
    int b = idx >> 16;
    int pix = idx & 0xFFFF;
    const float* base = in + (size_t)b * 3 * PLANE + pix;
    _Float16 h0 = (_Float16)base[0];
    _Float16 h1 = (_Float16)base[PLANE];
    _Float16 h2 = (_Float16)base[2 * PLANE];
    ushort4 u;
    u.x = __builtin_bit_cast(unsigned short, h0);
    u.y = __builtin_bit_cast(unsigned short, h1);
    u.z = __builtin_bit_cast(unsigned short, h2);
    u.w = 0;
    img[idx] = u;
}

__device__ __forceinline__ void acc3(float w, unsigned int pa, unsigned int pb,
                                     float& ax, float& ay, float& az) {
    __half2 ha = __builtin_bit_cast(__half2, pa);
    __half2 hb = __builtin_bit_cast(__half2, pb);
    ax = fmaf(w, __low2float(ha), ax);   // v_fma_mix_f32 (lo)
    ay = fmaf(w, __high2float(ha), ay);  // v_fma_mix_f32 (hi)
    az = fmaf(w, __low2float(hb), az);
}

// WIDE-STREAM kernel (round 8). Block = ONE output row (256 px), 4 waves
// k-split 21/20/20/20; LANE OWNS 4 CONSECUTIVE PIXELS (px = 4l..4l+3), so
// every offset/mask stream load is a global_load_dwordx4 (16 B/lane,
// 1 KB/wave-instruction): 3 loads per tap per wave instead of 12 dwords
// across 4 waves. Same bytes, 1/4 the vmcnt slots, 4x bytes-in-flight per
// slot -- directly raising the lines-in-flight/CU that rounds 0-7 measured
// as the binding constraint (~20-40 vs ~175 needed for peak).
//
// Bilinear from a zero-padded LDS tile (rows [ho-10,ho+10], cols [-10,266));
// tile row r == image row exactly, so unclamped index math is correct and
// out-of-image corners contribute 0 through the data (DCNv2 semantics).
// Rare escapes (|offset| > ~7): sticky flag + exact clamped/masked global
// redo. LDS (46.4K tile + 12K reduce) caps residency at 2 blocks/CU; no
// launch-bounds min-waves so VGPR can float (no spill risk).
__global__ __launch_bounds__(256) void dcn_kernel(
    const ushort4* __restrict__ img,
    const float* __restrict__ offset,
    const float* __restrict__ mask,
    const float* __restrict__ weight,
    const float* __restrict__ bias,
    float* __restrict__ out) {
    __shared__ uint2 tile[TABW];           // 46368 B zero-padded fp16 image
    __shared__ float red[3][4][256];       // 12288 B cross-wave reduce

    const int t = threadIdx.x;
    const int w = t >> 6;
    const int l = t & 63;
    const int b = blockIdx.y;
    const int ho = blockIdx.x;             // output row
    const int yb = ho - SLK;
    const ushort4* ib = img + (size_t)b * PLANE;

    // ---- stage zero-padded tile: 5796 cells, 23 iters of 256 threads ----
    for (int i = 0; i < 23; ++i) {
        int cid = t + i * 256;
        if (cid < TABW) {
            int r = cid / TCW;
            int c = cid - r * TCW;
            int iy = yb + r;
            int ix = c - SLK;
            unsigned int pa = 0, pb = 0;
            if (((unsigned)iy < (unsigned)HH) & ((unsigned)ix < (unsigned)WW)) {
                ushort4 u = ib[iy * WW + ix];
                pa = (unsigned int)u.x | ((unsigned int)u.y << 16);
                pb = (unsigned int)u.z;
            }
            tile[cid] = make_uint2(pa, pb);
        }
    }
    __syncthreads();

    // wave's tap range: [0,21) [21,41) [41,61) [61,81)
    const int kbeg = w * 20 + (w ? 1 : 0);
    const int nk = w ? 20 : 21;
    int ky = kbeg / 9;
    int kxi = kbeg - ky * 9;

    const float* obase = offset + (size_t)b * 2 * KK * PLANE
                         + (size_t)(2 * kbeg) * PLANE + (size_t)ho * WW;
    const float* mbase = mask + (size_t)b * KK * PLANE
                         + (size_t)kbeg * PLANE + (size_t)ho * WW;

    float ax[4] = {0.f, 0.f, 0.f, 0.f};
    float ay[4] = {0.f, 0.f, 0.f, 0.f};
    float az[4] = {0.f, 0.f, 0.f, 0.f};
    bool esc = false;

#pragma unroll 2
    for (int j = 0; j < nk; ++j) {
        // 3 wide stream loads: 16 B/lane, 1 KB/wave-instruction
        float4 dy4 = *(const float4*)(obase + (size_t)(2 * j) * PLANE + 4 * l);
        float4 dx4 = *(const float4*)(obase + (size_t)(2 * j + 1) * PLANE + 4 * l);
        float4 m4 = *(const float4*)(mbase + (size_t)j * PLANE + 4 * l);
        float wkv = weight[kbeg + j];      // wave-uniform s_load

        const float dyv[4] = {dy4.x, dy4.y, dy4.z, dy4.w};
        const float dxv[4] = {dx4.x, dx4.y, dx4.z, dx4.w};
        const float mv[4] = {m4.x, m4.y, m4.z, m4.w};

#pragma unroll
        for (int i = 0; i < 4; ++i) {
            const int wo = 4 * l + i;      // this pixel's output col
            float dy = dyv[i];
            float yf = floorf(dy);
            float wy = dy - yf;            // == fract(py)
            int r0 = (int)yf + ky + (SLK - 4);

            float fx = dxv[i] + (float)(kxi - 4);
            float xf = floorf(fx);
            float wx = fx - xf;
            int c0 = (int)xf + wo + SLK;

            bool ok = ((unsigned)r0 < (unsigned)(TR - 1)) &
                      ((unsigned)c0 < (unsigned)(TCW - 1));
            esc |= !ok;
            float mw = (ok ? mv[i] : 0.f) * wkv;  // cndmask; zero kills tap

            float w1y = wy * mw, w0y = mw - w1y;  // validity via data
            float u1 = 1.f - wx;
            float w00 = w0y * u1, w01 = w0y * wx;
            float w10 = w1y * u1, w11 = w1y * wx;

            int r0c = min(max(r0, 0), TR - 2);    // LDS read always safe
            int c0c = min(max(c0, 0), TCW - 2);
            const uint2* p = &tile[r0c * TCW + c0c];
            uint2 q00 = p[0];
            uint2 q01 = p[1];                     // ds_read2_b64 {0,1}
            uint2 q10 = p[TCW];
            uint2 q11 = p[TCW + 1];               // ds_read2_b64 on base+2208

            acc3(w00, q00.x, q00.y, ax[i], ay[i], az[i]);
            acc3(w01, q01.x, q01.y, ax[i], ay[i], az[i]);
            acc3(w10, q10.x, q10.y, ax[i], ay[i], az[i]);
            acc3(w11, q11.x, q11.y, ax[i], ay[i], az[i]);
        }

        if (++kxi == 9) {
            kxi = 0;
            ++ky;
        }
    }

    // ---- rare escapes: exact clamped + validity-masked global redo ----
    if (__builtin_expect(esc, 0)) {
#pragma unroll 1
        for (int j = 0; j < nk; ++j) {
            int k = kbeg + j;
            int kyy = k / 9;
            int kxx = k - kyy * 9;
#pragma unroll
            for (int i = 0; i < 4; ++i) {
                const int wo = 4 * l + i;
                float dy = obase[(size_t)(2 * j) * PLANE + wo];
                float dx = obase[(size_t)(2 * j + 1) * PLANE + wo];
                float m = mbase[(size_t)j * PLANE + wo];

                float yf = floorf(dy);
                int r0 = (int)yf + kyy + (SLK - 4);
                float fx = dx + (float)(kxx - 4);
                float xf = floorf(fx);
                int c0 = (int)xf + wo + SLK;
                bool ok = ((unsigned)r0 < (unsigned)(TR - 1)) &
                          ((unsigned)c0 < (unsigned)(TCW - 1));
                if (ok) continue;          // pass 1 handled it

                float wy = dy - yf;
                float wx = fx - xf;
                int y0 = (int)yf + ho - 4 + kyy;
                int x0 = (int)xf + wo + kxx - 4;
                int y1 = y0 + 1, x1 = x0 + 1;
                float mw = m * weight[k];
                float va0 = ((unsigned)y0 < (unsigned)HH) ? 1.f : 0.f;
                float va1 = ((unsigned)y1 < (unsigned)HH) ? 1.f : 0.f;
                float vb0 = ((unsigned)x0 < (unsigned)WW) ? 1.f : 0.f;
                float vb1 = ((unsigned)x1 < (unsigned)WW) ? 1.f : 0.f;
                float w1y = wy * mw, w0y = mw - w1y;
                float w00 = w0y * (1.f - wx) * va0 * vb0;
                float w01 = w0y * wx * va0 * vb1;
                float w10 = w1y * (1.f - wx) * va1 * vb0;
                float w11 = w1y * wx * va1 * vb1;
                int y0c = min(max(y0, 0), HH - 1);
                int y1c = min(max(y1, 0), HH - 1);
                int x0c = min(max(x0, 0), WW - 1);
                int x1c = min(max(x1, 0), WW - 1);
                ushort4 g00 = ib[y0c * WW + x0c];
                ushort4 g01 = ib[y0c * WW + x1c];
                ushort4 g10 = ib[y1c * WW + x0c];
                ushort4 g11 = ib[y1c * WW + x1c];
                acc3(w00, (unsigned int)g00.x | ((unsigned int)g00.y << 16), g00.z,
                     ax[i], ay[i], az[i]);
                acc3(w01, (unsigned int)g01.x | ((unsigned int)g01.y << 16), g01.z,
                     ax[i], ay[i], az[i]);
                acc3(w10, (unsigned int)g10.x | ((unsigned int)g10.y << 16), g10.z,
                     ax[i], ay[i], az[i]);
                acc3(w11, (unsigned int)g11.x | ((unsigned int)g11.y << 16), g11.z,
                     ax[i], ay[i], az[i]);
            }
        }
    }

    // ---- cross-wave reduce + write-out ----
#pragma unroll
    for (int i = 0; i < 4; ++i) {
        red[0][w][4 * l + i] = ax[i];
        red[1][w][4 * l + i] = ay[i];
        red[2][w][4 * l + i] = az[i];
    }
    __syncthreads();

    {
        float bs = bias[0];
        float* ob = out + (size_t)b * 3 * PLANE + (size_t)ho * WW + t;
        float s0 = red[0][0][t] + red[0][1][t] + red[0][2][t] + red[0][3][t];
        float s1 = red[1][0][t] + red[1][1][t] + red[1][2][t] + red[1][3][t];
        float s2 = red[2][0][t] + red[2][1][t] + red[2][2][t] + red[2][3][t];
        ob[0] = s0 + bs;
        ob[PLANE] = s1 + bs;
        ob[2 * PLANE] = s2 + bs;
    }
}

extern "C" void kernel_launch(void* const* d_in, const int* in_sizes, int n_in,
                              void* d_out, int out_size, void* d_ws, size_t ws_size,
                              hipStream_t stream) {
    const float* input = (const float*)d_in[0];
    const float* offset = (const float*)d_in[1];
    const float* mask = (const float*)d_in[2];
    const float* weight = (const float*)d_in[3];
    const float* bias = (const float*)d_in[4];
    float* out = (float*)d_out;

    const int B = in_sizes[0] / (3 * PLANE);  // 2
    ushort4* img = (ushort4*)d_ws;            // 1 MB packed fp16 image

    pack_kernel<<<B * PLANE / 256, 256, 0, stream>>>(input, img);
    dim3 grid(HH, B);                         // one block per output row
    dcn_kernel<<<grid, 256, 0, stream>>>(img, offset, mask, weight, bias, out);
}